// Round 6
// baseline (83.154 us; speedup 1.0000x reference)
//
#include <hip/hip_runtime.h>
#include <math.h>

#define TWO_PI 6.283185307179586f

// workspace layout (floats)
#define OFF_ET   0ull          // frames [be][f][4096] (inv-FFT output)
#define OFF_E    8388608ull    // spectra E [be][f][2049] float2
#define OFF_MAXP 16781312ull   // 256 partial maxima (2 per be)
#define OFF_Z    16782336ull   // packed Z' [be][f][2048] float2

__device__ __forceinline__ int swz(int n) { return n ^ ((n >> 5) & 31); }

// position of natural index k after DIF with radices [2,4,4,4,4,4]
__device__ __forceinline__ int permf(int k) {
    return ((k & 1) << 10) | (((k >> 1) & 3) << 8) | (((k >> 3) & 3) << 6)
         | (((k >> 5) & 3) << 4) | (((k >> 7) & 3) << 2) | ((k >> 9) & 3);
}

__device__ __forceinline__ void r4f_core(float* cr, float* ci, int p0, int p1, int p2, int p3,
                                         float c1, float s1, float c2, float s2, float c3, float s3) {
    float ar = cr[p0], ai = ci[p0];
    float br = cr[p1], bi = ci[p1];
    float crr = cr[p2], cri = ci[p2];
    float drr = cr[p3], dri = ci[p3];
    float u0r = ar + crr, u0i = ai + cri;
    float u1r = ar - crr, u1i = ai - cri;
    float u2r = br + drr, u2i = bi + dri;
    float u3r = br - drr, u3i = bi - dri;
    cr[p0] = u0r + u2r; ci[p0] = u0i + u2i;
    float z1r = u1r + u3i, z1i = u1i - u3r;            // u1 - i*u3
    cr[p1] = z1r * c1 + z1i * s1; ci[p1] = z1i * c1 - z1r * s1;
    float z2r = u0r - u2r, z2i = u0i - u2i;
    cr[p2] = z2r * c2 + z2i * s2; ci[p2] = z2i * c2 - z2r * s2;
    float z3r = u1r - u3i, z3i = u1i + u3r;            // u1 + i*u3
    cr[p3] = z3r * c3 + z3i * s3; ci[p3] = z3i * c3 - z3r * s3;
}

__device__ __forceinline__ void r4i_core(float* cr, float* ci, int p0, int p1, int p2, int p3,
                                         float c1, float s1, float c2, float s2, float c3, float s3) {
    float z0r = cr[p0], z0i = ci[p0];
    float z1r = cr[p1], z1i = ci[p1];
    float z2r = cr[p2], z2i = ci[p2];
    float z3r = cr[p3], z3i = ci[p3];
    float t1r = z1r * c1 - z1i * s1, t1i = z1i * c1 + z1r * s1;
    float t2r = z2r * c2 - z2i * s2, t2i = z2i * c2 + z2r * s2;
    float t3r = z3r * c3 - z3i * s3, t3i = z3i * c3 + z3r * s3;
    float u0r = z0r + t2r, u0i = z0i + t2i;
    float u1r = z0r - t2r, u1i = z0i - t2i;
    float u2r = t1r + t3r, u2i = t1i + t3i;
    float u3r = t1r - t3r, u3i = t1i - t3i;
    cr[p0] = u0r + u2r; ci[p0] = u0i + u2i;
    cr[p1] = u1r - u3i; ci[p1] = u1i + u3r;            // u1 + i*u3
    cr[p2] = u0r - u2r; ci[p2] = u0i - u2i;
    cr[p3] = u1r + u3i; ci[p3] = u1i - u3r;            // u1 - i*u3
}

// one radix-4 stage applied to all 4 buffers (shared indices + twiddles)
#define STAGE4(CORE, JEXPR, H, ANG)                                            \
    {                                                                          \
        int j_ = (JEXPR);                                                      \
        int p0 = swz(j_), p1 = swz(j_ + (H)), p2 = swz(j_ + 2 * (H)),          \
            p3 = swz(j_ + 3 * (H));                                            \
        float s1, c1; __sincosf((ANG), &s1, &c1);                              \
        float c2 = c1 * c1 - s1 * s1, s2 = 2.f * c1 * s1;                      \
        float c3 = c1 * c2 - s1 * s2, s3 = s1 * c2 + c1 * s2;                  \
        CORE(B + 0,     B + 2048,  p0, p1, p2, p3, c1, s1, c2, s2, c3, s3);    \
        CORE(B + 4096,  B + 6144,  p0, p1, p2, p3, c1, s1, c2, s2, c3, s3);    \
        CORE(B + 8192,  B + 10240, p0, p1, p2, p3, c1, s1, c2, s2, c3, s3);    \
        CORE(B + 12288, B + 14336, p0, p1, p2, p3, c1, s1, c2, s2, c3, s3);    \
    }                                                                          \
    __syncthreads();

// ---- fused: energy + 4x forward FFT, stage-interleaved (blocks 0..511)
//      | tf max reduction (blocks 512..767)
__global__ __launch_bounds__(512, 4) void k_fwd(const float* __restrict__ env,
                                                const float* __restrict__ noise,
                                                const float* __restrict__ tf,
                                                float* __restrict__ ws) {
    __shared__ float B[16384];   // 4 FFTs x (cr[2048], ci[2048]) = 64 KB
    int tid = threadIdx.x;
    int id = blockIdx.x;
    if (id < 512) {
        int xcd = id & 7, slot = id >> 3;
        int be = xcd * 16 + (slot >> 2);
        int fg = slot & 3;                       // f = fg*4 .. fg*4+3
        const float4* env4 = (const float4*)env;
        const float4* noi4 = (const float4*)noise;
        size_t base = (size_t)be * 16384 + fg;
        for (int it = 0; it < 8; ++it) {
            int n = it * 512 + tid;
            float4 e = env4[base + (size_t)n * 4];
            float4 z = noi4[base + (size_t)n * 4];
            float v0 = e.x * (z.x * 2.0f - 1.0f);
            float v1 = e.y * (z.y * 2.0f - 1.0f);
            float v2 = e.z * (z.z * 2.0f - 1.0f);
            float v3 = e.w * (z.w * 2.0f - 1.0f);
            int m = swz(n >> 1) + (n & 1) * 2048;   // cr at +0, ci at +2048
            B[m] = v0; B[4096 + m] = v1; B[8192 + m] = v2; B[12288 + m] = v3;
        }
        __syncthreads();
        // radix-2 DIF, h=1024 (twiddles shared across the 4 buffers)
#pragma unroll
        for (int it = 0; it < 2; ++it) {
            int i = tid + it * 512;
            int sj = swz(i), sjb = swz(i + 1024);
            float s, c; __sincosf((float)i * (TWO_PI / 2048.0f), &s, &c);
#pragma unroll
            for (int j4 = 0; j4 < 4; ++j4) {
                float* cr = B + j4 * 4096;
                float* ci = cr + 2048;
                float ar = cr[sj], ai = ci[sj], br = cr[sjb], bi = ci[sjb];
                float dr = ar - br, di = ai - bi;
                cr[sj] = ar + br; ci[sj] = ai + bi;
                cr[sjb] = dr * c + di * s; ci[sjb] = di * c - dr * s;
            }
        }
        __syncthreads();
        STAGE4(r4f_core, (tid >> 8) * 1024 + (tid & 255), 256, (float)(tid & 255) * (TWO_PI / 1024.0f));
        STAGE4(r4f_core, (tid >> 6) * 256 + (tid & 63), 64, (float)(tid & 63) * (TWO_PI / 256.0f));
        STAGE4(r4f_core, (tid & 31) * 64 + (tid >> 5), 16, (float)(tid >> 5) * (TWO_PI / 64.0f));
        STAGE4(r4f_core, (tid & 127) * 16 + (tid >> 7), 4, (float)(tid >> 7) * (TWO_PI / 16.0f));
        STAGE4(r4f_core, tid * 4, 1, 0.0f);
        // rfft unpack -> E, twiddles/indices shared across the 4 buffers
        float2* Ebase = (float2*)(ws + OFF_E) + (size_t)(be * 16 + fg * 4) * 2049;
        for (int it = 0; it < 3; ++it) {
            int k = tid + it * 512;
            if (k <= 1024) {
                int pk = swz(permf(k));
                int pm = swz(permf((2048 - k) & 2047));
                float s4, c4; __sincosf((float)k * (TWO_PI / 4096.0f), &s4, &c4);
#pragma unroll
                for (int j4 = 0; j4 < 4; ++j4) {
                    float* cr = B + j4 * 4096;
                    float* ci = cr + 2048;
                    float zkr = cr[pk], zki = ci[pk], zmr = cr[pm], zmi = ci[pm];
                    float xer = 0.5f * (zkr + zmr), xei = 0.5f * (zki - zmi);
                    float xor_ = 0.5f * (zki + zmi), xoi = 0.5f * (zmr - zkr);
                    float wr = xor_ * c4 + xoi * s4;
                    float wi = xoi * c4 - xor_ * s4;
                    float2* Eg = Ebase + (size_t)j4 * 2049;
                    Eg[k] = make_float2(xer + wr, xei + wi);
                    Eg[2048 - k] = make_float2(xer - wr, wi - xei);
                }
            }
        }
    } else {
        int bb = id - 512;                 // 0..255
        int be = bb >> 1, c = bb & 1;
        const float4* ab4 = (const float4*)(tf + (size_t)be * 65568);
        float mx = 0.f;
        int start = c * 4098, end = start + 4098;
        for (int u = start + tid; u < end; u += 512) {
            int bin = u >> 2, e = u & 3;
            float4 A = ab4[bin * 8 + e];
            float4 Bv = ab4[bin * 8 + e + 4];
            mx = fmaxf(mx, fmaxf(fmaxf(A.x * A.x + Bv.x * Bv.x, A.y * A.y + Bv.y * Bv.y),
                                 fmaxf(A.z * A.z + Bv.z * Bv.z, A.w * A.w + Bv.w * Bv.w)));
        }
        B[tid] = mx;
        __syncthreads();
        for (int s = 256; s > 0; s >>= 1) {
            if (tid < s) B[tid] = fmaxf(B[tid], B[tid + s]);
            __syncthreads();
        }
        if (tid == 0) ws[OFF_MAXP + bb] = B[0];
    }
}

// ---- per-bin recurrence on pair (k, 2048-k) + fused irfft pre-pack -> Z' natural order
__global__ __launch_bounds__(256) void k_recur(const float* __restrict__ tf,
                                               float* __restrict__ ws) {
    __shared__ float sm2lo[256 * 17], simlo[256 * 17];
    __shared__ float sm2hi[256 * 17], simhi[256 * 17];
    int tid = threadIdx.x;
    int be = blockIdx.y;
    int k0 = blockIdx.x << 8;          // 0,256,512,768
    int hi0 = 1793 - k0;               // hi bins [hi0, hi0+255]
    const float* tfb = tf + (size_t)be * 65568;
    const float4* ab4 = (const float4*)tfb;
    const float4* im4 = (const float4*)(tfb + 32784);

    for (int u = tid; u < 2048; u += 256) {
        int half = u >> 10, v = u & 1023;
        int g = v >> 2, e = v & 3;
        int bin = half ? (hi0 + g) : (k0 + g);
        float4 A = ab4[bin * 8 + e];
        float4 Bv = ab4[bin * 8 + e + 4];
        float4 I = im4[bin * 4 + e];
        int o = g * 17 + e * 4;
        float* sm = half ? sm2hi : sm2lo;
        float* si = half ? simhi : simlo;
        sm[o + 0] = A.x * A.x + Bv.x * Bv.x;
        sm[o + 1] = A.y * A.y + Bv.y * Bv.y;
        sm[o + 2] = A.z * A.z + Bv.z * Bv.z;
        sm[o + 3] = A.w * A.w + Bv.w * Bv.w;
        si[o + 0] = I.x; si[o + 1] = I.y; si[o + 2] = I.z; si[o + 3] = I.w;
    }
    __syncthreads();

    int k = k0 + tid;
    int m = 2048 - k;
    int rhi = 255 - tid;
    const float* mp = ws + OFF_MAXP + be * 2;
    float m2x = fmaxf(mp[0], mp[1]);
    float rden = 1.0f / (sqrtf(m2x) + 1e-8f);
    const float2* Eb = (const float2*)(ws + OFF_E) + (size_t)be * 16 * 2049;
    float2* Zb = (float2*)(ws + OFF_Z) + (size_t)be * 16 * 2048;
    float2 evlo[16], evhi[16];
#pragma unroll
    for (int f = 0; f < 16; ++f) {
        evlo[f] = Eb[(size_t)f * 2049 + k];
        evhi[f] = Eb[(size_t)f * 2049 + m];
    }
    float ym = (k == 0) ? 0.0f : 1.0f;
    float s4, c4; __sincosf((float)k * (TWO_PI / 4096.0f), &s4, &c4);
    const float SCL = 1.0f / 2048.0f;
    float srl = 0.f, sil = 0.f, srh = 0.f, sih = 0.f;
#pragma unroll
    for (int f = 0; f < 16; ++f) {
        float mh = sqrtf(sm2lo[tid * 17 + f]) * rden;
        float ph = atan2f(simlo[tid * 17 + f], mh) * 3.14159265358979f;
        float sp, cp; __sincosf(ph, &sp, &cp);
        float Tr = mh * cp, Ti = mh * sp;
        sil *= ym;
        srl += evlo[f].x; sil += evlo[f].y;
        float nr = srl * Tr - sil * Ti;
        sil = srl * Ti + sil * Tr; srl = nr;
        float mh2 = sqrtf(sm2hi[rhi * 17 + f]) * rden;
        float ph2 = atan2f(simhi[rhi * 17 + f], mh2) * 3.14159265358979f;
        float sp2, cp2; __sincosf(ph2, &sp2, &cp2);
        float Tr2 = mh2 * cp2, Ti2 = mh2 * sp2;
        sih *= ym;
        srh += evhi[f].x; sih += evhi[f].y;
        float nr2 = srh * Tr2 - sih * Ti2;
        sih = srh * Ti2 + sih * Tr2; srh = nr2;
        float2* Zf = Zb + (size_t)f * 2048;
        if (k == 0) {
            float y0 = srl * SCL, yn = srh * SCL;
            Zf[0] = make_float2(0.5f * (y0 + yn), 0.5f * (y0 - yn));
        } else {
            float ykr = srl * SCL, yki = sil * SCL;
            float ymr = srh * SCL, ymi = sih * SCL;
            float er = 0.5f * (ykr + ymr), ei = 0.5f * (yki - ymi);
            float dr = ykr - ymr, di = yki + ymi;
            float orr = 0.5f * (dr * c4 - di * s4);
            float oi = 0.5f * (dr * s4 + di * c4);
            Zf[k] = make_float2(er - oi, ei + orr);
            Zf[m] = make_float2(er + oi, orr - ei);
        }
    }
    if (k0 == 0 && tid == 0) {   // bin 1024 (self-paired)
        float sr = 0.f, si = 0.f;
#pragma unroll
        for (int f = 0; f < 16; ++f) {
            float a = tfb[1024 * 32 + f];
            float b = tfb[1024 * 32 + 16 + f];
            float im = tfb[32784 + 1024 * 16 + f];
            float mh = sqrtf(a * a + b * b) * rden;
            float ph = atan2f(im, mh) * 3.14159265358979f;
            float sp, cp; __sincosf(ph, &sp, &cp);
            float Tr = mh * cp, Ti = mh * sp;
            float2 e = Eb[(size_t)f * 2049 + 1024];
            sr += e.x; si += e.y;
            float nr = sr * Tr - si * Ti;
            si = sr * Ti + si * Tr; sr = nr;
            Zb[(size_t)f * 2048 + 1024] = make_float2(sr * SCL, -si * SCL);
        }
    }
}

// ---- inverse FFT: 4 frames per block, stage-interleaved
__global__ __launch_bounds__(512, 4) void k_fft_inv(float* __restrict__ ws) {
    __shared__ float B[16384];
    int tid = threadIdx.x;
    int be = blockIdx.x >> 2, fg = blockIdx.x & 3;
    const float2* Zbase = (const float2*)(ws + OFF_Z) + (size_t)(be * 16 + fg * 4) * 2048;
#pragma unroll
    for (int j4 = 0; j4 < 4; ++j4) {
        const float4* Zg = (const float4*)(Zbase + (size_t)j4 * 2048);
        float* cr = B + j4 * 4096;
        float* ci = cr + 2048;
#pragma unroll
        for (int it = 0; it < 2; ++it) {
            int idx = tid + it * 512;
            float4 v = Zg[idx];
            int n0 = idx * 2;
            int p0 = swz(permf(n0)), p1 = swz(permf(n0 + 1));
            cr[p0] = v.x; ci[p0] = v.y;
            cr[p1] = v.z; ci[p1] = v.w;
        }
    }
    __syncthreads();
    STAGE4(r4i_core, tid * 4, 1, 0.0f);
    STAGE4(r4i_core, (tid & 127) * 16 + (tid >> 7), 4, (float)(tid >> 7) * (TWO_PI / 16.0f));
    STAGE4(r4i_core, (tid & 31) * 64 + (tid >> 5), 16, (float)(tid >> 5) * (TWO_PI / 64.0f));
    STAGE4(r4i_core, (tid >> 6) * 256 + (tid & 63), 64, (float)(tid & 63) * (TWO_PI / 256.0f));
    STAGE4(r4i_core, (tid >> 8) * 1024 + (tid & 255), 256, (float)(tid & 255) * (TWO_PI / 1024.0f));
    // radix-2 DIT, h=1024 (twiddles shared)
#pragma unroll
    for (int it = 0; it < 2; ++it) {
        int i = tid + it * 512;
        int sj = swz(i), sjb = swz(i + 1024);
        float s, c; __sincosf((float)i * (TWO_PI / 2048.0f), &s, &c);
#pragma unroll
        for (int j4 = 0; j4 < 4; ++j4) {
            float* cr = B + j4 * 4096;
            float* ci = cr + 2048;
            float br = cr[sjb], bi = ci[sjb];
            float tr = br * c - bi * s, ti2 = br * s + bi * c;
            float ar = cr[sj], ai = ci[sj];
            cr[sj] = ar + tr;  ci[sj] = ai + ti2;
            cr[sjb] = ar - tr; ci[sjb] = ai - ti2;
        }
    }
    __syncthreads();
    float2* Fbase = (float2*)(ws + OFF_ET) + (size_t)(be * 16 + fg * 4) * 2048;
#pragma unroll
    for (int j4 = 0; j4 < 4; ++j4) {
        float* cr = B + j4 * 4096;
        float* ci = cr + 2048;
        float2* Fg = Fbase + (size_t)j4 * 2048;
#pragma unroll
        for (int it = 0; it < 4; ++it) {
            int m = tid + it * 512;
            Fg[m] = make_float2(cr[swz(m)], ci[swz(m)]);
        }
    }
}

// ---- gather + fused overlap-add (b uniform per block -> scalar indices)
__global__ __launch_bounds__(256) void k_segment(const float* __restrict__ ws,
                                                 const int* __restrict__ indices,
                                                 float* __restrict__ out) {
    __shared__ int ste[16];
    int tid = threadIdx.x;
    int b = blockIdx.y;
    if (tid < 16) ste[tid] = indices[b * 16 + tid] * 256;
    __syncthreads();
    int g = blockIdx.x * 256 + tid;
    int t = g << 2;
    const float* F = ws + OFF_ET;
    float4 acc = make_float4(0.f, 0.f, 0.f, 0.f);
#pragma unroll
    for (int e = 0; e < 16; ++e) {
        int te = ste[e];
        if (t >= te) {
            int d = t - te;
            int j = d >> 11, r = d & 2047;
            size_t base = (size_t)(b * 16 + e) * 65536;
            float4 v = *(const float4*)(F + base + j * 4096 + r);
            acc.x += v.x; acc.y += v.y; acc.z += v.z; acc.w += v.w;
            if (j >= 1) {
                float4 w = *(const float4*)(F + base + (j - 1) * 4096 + 2048 + r);
                acc.x += w.x; acc.y += w.y; acc.z += w.z; acc.w += w.w;
            }
        }
    }
    ((float4*)out)[(size_t)b * 8192 + g] = acc;
}

extern "C" void kernel_launch(void* const* d_in, const int* in_sizes, int n_in,
                              void* d_out, int out_size, void* d_ws, size_t ws_size,
                              hipStream_t stream) {
    const float* env = (const float*)d_in[0];
    const float* tf = (const float*)d_in[1];
    const float* noise = (const float*)d_in[2];
    const int* indices = (const int*)d_in[3];
    float* ws = (float*)d_ws;
    float* out = (float*)d_out;

    k_fwd<<<dim3(768), dim3(512), 0, stream>>>(env, noise, tf, ws);
    k_recur<<<dim3(4, 128), dim3(256), 0, stream>>>(tf, ws);
    k_fft_inv<<<dim3(512), dim3(512), 0, stream>>>(ws);
    k_segment<<<dim3(32, 8), dim3(256), 0, stream>>>(ws, indices, out);
}

// Round 7
// 82.428 us; speedup vs baseline: 1.0088x; 1.0088x over previous
//
#include <hip/hip_runtime.h>
#include <math.h>

#define TWO_PI 6.283185307179586f

// workspace layout (floats)
#define OFF_ET   0ull          // frames [be][f][4096] (inv-FFT output)
#define OFF_E    8388608ull    // spectra E [be][f][2049] float2
#define OFF_MAXP 16781312ull   // 256 partial maxima (2 per be)
#define OFF_Z    16782336ull   // packed Z' [be][f][2048] float2

__device__ __forceinline__ int swz(int n) { return n ^ ((n >> 5) & 31); }

// position of natural index k after DIF with radices [2,4,4,4,4,4]
__device__ __forceinline__ int permf(int k) {
    return ((k & 1) << 10) | (((k >> 1) & 3) << 8) | (((k >> 3) & 3) << 6)
         | (((k >> 5) & 3) << 4) | (((k >> 7) & 3) << 2) | ((k >> 9) & 3);
}

__device__ __forceinline__ void r4f_core(float* cr, float* ci, int p0, int p1, int p2, int p3,
                                         float c1, float s1, float c2, float s2, float c3, float s3) {
    float ar = cr[p0], ai = ci[p0];
    float br = cr[p1], bi = ci[p1];
    float crr = cr[p2], cri = ci[p2];
    float drr = cr[p3], dri = ci[p3];
    float u0r = ar + crr, u0i = ai + cri;
    float u1r = ar - crr, u1i = ai - cri;
    float u2r = br + drr, u2i = bi + dri;
    float u3r = br - drr, u3i = bi - dri;
    cr[p0] = u0r + u2r; ci[p0] = u0i + u2i;
    float z1r = u1r + u3i, z1i = u1i - u3r;            // u1 - i*u3
    cr[p1] = z1r * c1 + z1i * s1; ci[p1] = z1i * c1 - z1r * s1;
    float z2r = u0r - u2r, z2i = u0i - u2i;
    cr[p2] = z2r * c2 + z2i * s2; ci[p2] = z2i * c2 - z2r * s2;
    float z3r = u1r - u3i, z3i = u1i + u3r;            // u1 + i*u3
    cr[p3] = z3r * c3 + z3i * s3; ci[p3] = z3i * c3 - z3r * s3;
}

__device__ __forceinline__ void r4i_core(float* cr, float* ci, int p0, int p1, int p2, int p3,
                                         float c1, float s1, float c2, float s2, float c3, float s3) {
    float z0r = cr[p0], z0i = ci[p0];
    float z1r = cr[p1], z1i = ci[p1];
    float z2r = cr[p2], z2i = ci[p2];
    float z3r = cr[p3], z3i = ci[p3];
    float t1r = z1r * c1 - z1i * s1, t1i = z1i * c1 + z1r * s1;
    float t2r = z2r * c2 - z2i * s2, t2i = z2i * c2 + z2r * s2;
    float t3r = z3r * c3 - z3i * s3, t3i = z3i * c3 + z3r * s3;
    float u0r = z0r + t2r, u0i = z0i + t2i;
    float u1r = z0r - t2r, u1i = z0i - t2i;
    float u2r = t1r + t3r, u2i = t1i + t3i;
    float u3r = t1r - t3r, u3i = t1i - t3i;
    cr[p0] = u0r + u2r; ci[p0] = u0i + u2i;
    cr[p1] = u1r - u3i; ci[p1] = u1i + u3r;            // u1 + i*u3
    cr[p2] = u0r - u2r; ci[p2] = u0i - u2i;
    cr[p3] = u1r + u3i; ci[p3] = u1i - u3r;            // u1 - i*u3
}

// one radix-4 stage over 4 buffers with 1024 threads: thread handles global
// butterfly b = tid and tid+1024; buffer = b>>9, butterfly-in-FFT i_ = b&511.
// Wave-consecutive lanes stay within one buffer -> LDS pattern unchanged.
#define STAGE4X(CORE, JEXPR, H, ANGEXPR)                                       \
    {                                                                          \
        _Pragma("unroll")                                                      \
        for (int half_ = 0; half_ < 2; ++half_) {                              \
            int b_ = tid + half_ * 1024;                                       \
            int i_ = b_ & 511;                                                 \
            float* cr_ = B + (b_ >> 9) * 4096;                                 \
            int j_ = (JEXPR);                                                  \
            int p0 = swz(j_), p1 = swz(j_ + (H)), p2 = swz(j_ + 2 * (H)),      \
                p3 = swz(j_ + 3 * (H));                                        \
            float s1, c1; __sincosf((ANGEXPR), &s1, &c1);                      \
            float c2 = c1 * c1 - s1 * s1, s2 = 2.f * c1 * s1;                  \
            float c3 = c1 * c2 - s1 * s2, s3 = s1 * c2 + c1 * s2;              \
            CORE(cr_, cr_ + 2048, p0, p1, p2, p3, c1, s1, c2, s2, c3, s3);     \
        }                                                                      \
    }                                                                          \
    __syncthreads();

// ---- fused: energy + 4x forward FFT (blocks 0..511) | tf max (512..767)
__global__ __launch_bounds__(1024, 8) void k_fwd(const float* __restrict__ env,
                                                 const float* __restrict__ noise,
                                                 const float* __restrict__ tf,
                                                 float* __restrict__ ws) {
    __shared__ float B[16384];   // 4 FFTs x (cr[2048], ci[2048]) = 64 KB
    int tid = threadIdx.x;
    int id = blockIdx.x;
    if (id < 512) {
        int xcd = id & 7, slot = id >> 3;
        int be = xcd * 16 + (slot >> 2);
        int fg = slot & 3;                       // f = fg*4 .. fg*4+3
        const float4* env4 = (const float4*)env;
        const float4* noi4 = (const float4*)noise;
        size_t base = (size_t)be * 16384 + fg;
#pragma unroll
        for (int it = 0; it < 4; ++it) {
            int n = it * 1024 + tid;
            float4 e = env4[base + (size_t)n * 4];
            float4 z = noi4[base + (size_t)n * 4];
            float v0 = e.x * (z.x * 2.0f - 1.0f);
            float v1 = e.y * (z.y * 2.0f - 1.0f);
            float v2 = e.z * (z.z * 2.0f - 1.0f);
            float v3 = e.w * (z.w * 2.0f - 1.0f);
            int m = swz(n >> 1) + (n & 1) * 2048;   // cr at +0, ci at +2048
            B[m] = v0; B[4096 + m] = v1; B[8192 + m] = v2; B[12288 + m] = v3;
        }
        __syncthreads();
        // radix-2 DIF, h=1024: i = tid in [0,1024), twiddle shared across buffers
        {
            int i = tid;
            int sj = swz(i), sjb = swz(i + 1024);
            float s, c; __sincosf((float)i * (TWO_PI / 2048.0f), &s, &c);
#pragma unroll
            for (int j4 = 0; j4 < 4; ++j4) {
                float* cr = B + j4 * 4096;
                float* ci = cr + 2048;
                float ar = cr[sj], ai = ci[sj], br = cr[sjb], bi = ci[sjb];
                float dr = ar - br, di = ai - bi;
                cr[sj] = ar + br; ci[sj] = ai + bi;
                cr[sjb] = dr * c + di * s; ci[sjb] = di * c - dr * s;
            }
        }
        __syncthreads();
        STAGE4X(r4f_core, (i_ >> 8) * 1024 + (i_ & 255), 256, (float)(i_ & 255) * (TWO_PI / 1024.0f));
        STAGE4X(r4f_core, (i_ >> 6) * 256 + (i_ & 63), 64, (float)(i_ & 63) * (TWO_PI / 256.0f));
        STAGE4X(r4f_core, (i_ & 31) * 64 + (i_ >> 5), 16, (float)(i_ >> 5) * (TWO_PI / 64.0f));
        STAGE4X(r4f_core, (i_ & 127) * 16 + (i_ >> 7), 4, (float)(i_ >> 7) * (TWO_PI / 16.0f));
        STAGE4X(r4f_core, i_ * 4, 1, 0.0f);
        // rfft unpack -> E (indices/twiddles shared across the 4 buffers)
        float2* Ebase = (float2*)(ws + OFF_E) + (size_t)(be * 16 + fg * 4) * 2049;
        for (int k = tid; k <= 1024; k += 1024) {
            int pk = swz(permf(k));
            int pm = swz(permf((2048 - k) & 2047));
            float s4, c4; __sincosf((float)k * (TWO_PI / 4096.0f), &s4, &c4);
#pragma unroll
            for (int j4 = 0; j4 < 4; ++j4) {
                float* cr = B + j4 * 4096;
                float* ci = cr + 2048;
                float zkr = cr[pk], zki = ci[pk], zmr = cr[pm], zmi = ci[pm];
                float xer = 0.5f * (zkr + zmr), xei = 0.5f * (zki - zmi);
                float xor_ = 0.5f * (zki + zmi), xoi = 0.5f * (zmr - zkr);
                float wr = xor_ * c4 + xoi * s4;
                float wi = xoi * c4 - xor_ * s4;
                float2* Eg = Ebase + (size_t)j4 * 2049;
                Eg[k] = make_float2(xer + wr, xei + wi);
                Eg[2048 - k] = make_float2(xer - wr, wi - xei);
            }
        }
    } else {
        int bb = id - 512;                 // 0..255
        int be = bb >> 1, c = bb & 1;
        const float4* ab4 = (const float4*)(tf + (size_t)be * 65568);
        float mx = 0.f;
        int start = c * 4098, end = start + 4098;
        for (int u = start + tid; u < end; u += 1024) {
            int bin = u >> 2, e = u & 3;
            float4 A = ab4[bin * 8 + e];
            float4 Bv = ab4[bin * 8 + e + 4];
            mx = fmaxf(mx, fmaxf(fmaxf(A.x * A.x + Bv.x * Bv.x, A.y * A.y + Bv.y * Bv.y),
                                 fmaxf(A.z * A.z + Bv.z * Bv.z, A.w * A.w + Bv.w * Bv.w)));
        }
        B[tid] = mx;
        __syncthreads();
        for (int s = 512; s > 0; s >>= 1) {
            if (tid < s) B[tid] = fmaxf(B[tid], B[tid + s]);
            __syncthreads();
        }
        if (tid == 0) ws[OFF_MAXP + bb] = B[0];
    }
}

// ---- per-bin recurrence on pair (k, 2048-k) + fused irfft pre-pack -> Z' natural order
__global__ __launch_bounds__(256) void k_recur(const float* __restrict__ tf,
                                               float* __restrict__ ws) {
    __shared__ float sm2lo[256 * 17], simlo[256 * 17];
    __shared__ float sm2hi[256 * 17], simhi[256 * 17];
    int tid = threadIdx.x;
    int be = blockIdx.y;
    int k0 = blockIdx.x << 8;          // 0,256,512,768
    int hi0 = 1793 - k0;               // hi bins [hi0, hi0+255]
    const float* tfb = tf + (size_t)be * 65568;
    const float4* ab4 = (const float4*)tfb;
    const float4* im4 = (const float4*)(tfb + 32784);

    for (int u = tid; u < 2048; u += 256) {
        int half = u >> 10, v = u & 1023;
        int g = v >> 2, e = v & 3;
        int bin = half ? (hi0 + g) : (k0 + g);
        float4 A = ab4[bin * 8 + e];
        float4 Bv = ab4[bin * 8 + e + 4];
        float4 I = im4[bin * 4 + e];
        int o = g * 17 + e * 4;
        float* sm = half ? sm2hi : sm2lo;
        float* si = half ? simhi : simlo;
        sm[o + 0] = A.x * A.x + Bv.x * Bv.x;
        sm[o + 1] = A.y * A.y + Bv.y * Bv.y;
        sm[o + 2] = A.z * A.z + Bv.z * Bv.z;
        sm[o + 3] = A.w * A.w + Bv.w * Bv.w;
        si[o + 0] = I.x; si[o + 1] = I.y; si[o + 2] = I.z; si[o + 3] = I.w;
    }
    __syncthreads();

    int k = k0 + tid;
    int m = 2048 - k;
    int rhi = 255 - tid;
    const float* mp = ws + OFF_MAXP + be * 2;
    float m2x = fmaxf(mp[0], mp[1]);
    float rden = 1.0f / (sqrtf(m2x) + 1e-8f);
    const float2* Eb = (const float2*)(ws + OFF_E) + (size_t)be * 16 * 2049;
    float2* Zb = (float2*)(ws + OFF_Z) + (size_t)be * 16 * 2048;
    float2 evlo[16], evhi[16];
#pragma unroll
    for (int f = 0; f < 16; ++f) {
        evlo[f] = Eb[(size_t)f * 2049 + k];
        evhi[f] = Eb[(size_t)f * 2049 + m];
    }
    float ym = (k == 0) ? 0.0f : 1.0f;
    float s4, c4; __sincosf((float)k * (TWO_PI / 4096.0f), &s4, &c4);
    const float SCL = 1.0f / 2048.0f;
    float srl = 0.f, sil = 0.f, srh = 0.f, sih = 0.f;
#pragma unroll
    for (int f = 0; f < 16; ++f) {
        float mh = sqrtf(sm2lo[tid * 17 + f]) * rden;
        float ph = atan2f(simlo[tid * 17 + f], mh) * 3.14159265358979f;
        float sp, cp; __sincosf(ph, &sp, &cp);
        float Tr = mh * cp, Ti = mh * sp;
        sil *= ym;
        srl += evlo[f].x; sil += evlo[f].y;
        float nr = srl * Tr - sil * Ti;
        sil = srl * Ti + sil * Tr; srl = nr;
        float mh2 = sqrtf(sm2hi[rhi * 17 + f]) * rden;
        float ph2 = atan2f(simhi[rhi * 17 + f], mh2) * 3.14159265358979f;
        float sp2, cp2; __sincosf(ph2, &sp2, &cp2);
        float Tr2 = mh2 * cp2, Ti2 = mh2 * sp2;
        sih *= ym;
        srh += evhi[f].x; sih += evhi[f].y;
        float nr2 = srh * Tr2 - sih * Ti2;
        sih = srh * Ti2 + sih * Tr2; srh = nr2;
        float2* Zf = Zb + (size_t)f * 2048;
        if (k == 0) {
            float y0 = srl * SCL, yn = srh * SCL;
            Zf[0] = make_float2(0.5f * (y0 + yn), 0.5f * (y0 - yn));
        } else {
            float ykr = srl * SCL, yki = sil * SCL;
            float ymr = srh * SCL, ymi = sih * SCL;
            float er = 0.5f * (ykr + ymr), ei = 0.5f * (yki - ymi);
            float dr = ykr - ymr, di = yki + ymi;
            float orr = 0.5f * (dr * c4 - di * s4);
            float oi = 0.5f * (dr * s4 + di * c4);
            Zf[k] = make_float2(er - oi, ei + orr);
            Zf[m] = make_float2(er + oi, orr - ei);
        }
    }
    if (k0 == 0 && tid == 0) {   // bin 1024 (self-paired)
        float sr = 0.f, si = 0.f;
#pragma unroll
        for (int f = 0; f < 16; ++f) {
            float a = tfb[1024 * 32 + f];
            float b = tfb[1024 * 32 + 16 + f];
            float im = tfb[32784 + 1024 * 16 + f];
            float mh = sqrtf(a * a + b * b) * rden;
            float ph = atan2f(im, mh) * 3.14159265358979f;
            float sp, cp; __sincosf(ph, &sp, &cp);
            float Tr = mh * cp, Ti = mh * sp;
            float2 e = Eb[(size_t)f * 2049 + 1024];
            sr += e.x; si += e.y;
            float nr = sr * Tr - si * Ti;
            si = sr * Ti + si * Tr; sr = nr;
            Zb[(size_t)f * 2048 + 1024] = make_float2(sr * SCL, -si * SCL);
        }
    }
}

// ---- inverse FFT: 4 frames per block, 1024 threads
__global__ __launch_bounds__(1024, 8) void k_fft_inv(float* __restrict__ ws) {
    __shared__ float B[16384];
    int tid = threadIdx.x;
    int be = blockIdx.x >> 2, fg = blockIdx.x & 3;
    const float2* Zbase = (const float2*)(ws + OFF_Z) + (size_t)(be * 16 + fg * 4) * 2048;
#pragma unroll
    for (int j4 = 0; j4 < 4; ++j4) {
        const float4* Zg = (const float4*)(Zbase + (size_t)j4 * 2048);
        float* cr = B + j4 * 4096;
        float* ci = cr + 2048;
        int idx = tid;
        float4 v = Zg[idx];
        int n0 = idx * 2;
        int p0 = swz(permf(n0)), p1 = swz(permf(n0 + 1));
        cr[p0] = v.x; ci[p0] = v.y;
        cr[p1] = v.z; ci[p1] = v.w;
    }
    __syncthreads();
    STAGE4X(r4i_core, i_ * 4, 1, 0.0f);
    STAGE4X(r4i_core, (i_ & 127) * 16 + (i_ >> 7), 4, (float)(i_ >> 7) * (TWO_PI / 16.0f));
    STAGE4X(r4i_core, (i_ & 31) * 64 + (i_ >> 5), 16, (float)(i_ >> 5) * (TWO_PI / 64.0f));
    STAGE4X(r4i_core, (i_ >> 6) * 256 + (i_ & 63), 64, (float)(i_ & 63) * (TWO_PI / 256.0f));
    STAGE4X(r4i_core, (i_ >> 8) * 1024 + (i_ & 255), 256, (float)(i_ & 255) * (TWO_PI / 1024.0f));
    // radix-2 DIT, h=1024 (twiddle shared across buffers)
    {
        int i = tid;
        int sj = swz(i), sjb = swz(i + 1024);
        float s, c; __sincosf((float)i * (TWO_PI / 2048.0f), &s, &c);
#pragma unroll
        for (int j4 = 0; j4 < 4; ++j4) {
            float* cr = B + j4 * 4096;
            float* ci = cr + 2048;
            float br = cr[sjb], bi = ci[sjb];
            float tr = br * c - bi * s, ti2 = br * s + bi * c;
            float ar = cr[sj], ai = ci[sj];
            cr[sj] = ar + tr;  ci[sj] = ai + ti2;
            cr[sjb] = ar - tr; ci[sjb] = ai - ti2;
        }
    }
    __syncthreads();
    float2* Fbase = (float2*)(ws + OFF_ET) + (size_t)(be * 16 + fg * 4) * 2048;
#pragma unroll
    for (int j4 = 0; j4 < 4; ++j4) {
        float* cr = B + j4 * 4096;
        float* ci = cr + 2048;
        float2* Fg = Fbase + (size_t)j4 * 2048;
#pragma unroll
        for (int it = 0; it < 2; ++it) {
            int m = tid + it * 1024;
            Fg[m] = make_float2(cr[swz(m)], ci[swz(m)]);
        }
    }
}

// ---- gather + fused overlap-add (b uniform per block -> scalar indices)
__global__ __launch_bounds__(256) void k_segment(const float* __restrict__ ws,
                                                 const int* __restrict__ indices,
                                                 float* __restrict__ out) {
    __shared__ int ste[16];
    int tid = threadIdx.x;
    int b = blockIdx.y;
    if (tid < 16) ste[tid] = indices[b * 16 + tid] * 256;
    __syncthreads();
    int g = blockIdx.x * 256 + tid;
    int t = g << 2;
    const float* F = ws + OFF_ET;
    float4 acc = make_float4(0.f, 0.f, 0.f, 0.f);
#pragma unroll
    for (int e = 0; e < 16; ++e) {
        int te = ste[e];
        if (t >= te) {
            int d = t - te;
            int j = d >> 11, r = d & 2047;
            size_t base = (size_t)(b * 16 + e) * 65536;
            float4 v = *(const float4*)(F + base + j * 4096 + r);
            acc.x += v.x; acc.y += v.y; acc.z += v.z; acc.w += v.w;
            if (j >= 1) {
                float4 w = *(const float4*)(F + base + (j - 1) * 4096 + 2048 + r);
                acc.x += w.x; acc.y += w.y; acc.z += w.z; acc.w += w.w;
            }
        }
    }
    ((float4*)out)[(size_t)b * 8192 + g] = acc;
}

extern "C" void kernel_launch(void* const* d_in, const int* in_sizes, int n_in,
                              void* d_out, int out_size, void* d_ws, size_t ws_size,
                              hipStream_t stream) {
    const float* env = (const float*)d_in[0];
    const float* tf = (const float*)d_in[1];
    const float* noise = (const float*)d_in[2];
    const int* indices = (const int*)d_in[3];
    float* ws = (float*)d_ws;
    float* out = (float*)d_out;

    k_fwd<<<dim3(768), dim3(1024), 0, stream>>>(env, noise, tf, ws);
    k_recur<<<dim3(4, 128), dim3(256), 0, stream>>>(tf, ws);
    k_fft_inv<<<dim3(512), dim3(1024), 0, stream>>>(ws);
    k_segment<<<dim3(32, 8), dim3(256), 0, stream>>>(ws, indices, out);
}

// Round 8
// 82.249 us; speedup vs baseline: 1.0110x; 1.0022x over previous
//
#include <hip/hip_runtime.h>
#include <math.h>

#define TWO_PI 6.283185307179586f

// workspace layout (floats)
#define OFF_ET   0ull          // frames [be][f][4096] (inv-FFT output)
#define OFF_E    8388608ull    // spectra E [be][f][2049] float2
#define OFF_MAXP 16781312ull   // 512 partial maxima (4 per be)
#define OFF_Z    16782336ull   // packed Z' [be][f][2048] float2

__device__ __forceinline__ int swz(int n) { return n ^ ((n >> 5) & 31); }

// position of natural index k after DIF with radices [2,4,4,4,4,4]
__device__ __forceinline__ int permf(int k) {
    return ((k & 1) << 10) | (((k >> 1) & 3) << 8) | (((k >> 3) & 3) << 6)
         | (((k >> 5) & 3) << 4) | (((k >> 7) & 3) << 2) | ((k >> 9) & 3);
}

__device__ __forceinline__ void r4f_core(float* cr, float* ci, int p0, int p1, int p2, int p3,
                                         float c1, float s1, float c2, float s2, float c3, float s3) {
    float ar = cr[p0], ai = ci[p0];
    float br = cr[p1], bi = ci[p1];
    float crr = cr[p2], cri = ci[p2];
    float drr = cr[p3], dri = ci[p3];
    float u0r = ar + crr, u0i = ai + cri;
    float u1r = ar - crr, u1i = ai - cri;
    float u2r = br + drr, u2i = bi + dri;
    float u3r = br - drr, u3i = bi - dri;
    cr[p0] = u0r + u2r; ci[p0] = u0i + u2i;
    float z1r = u1r + u3i, z1i = u1i - u3r;            // u1 - i*u3
    cr[p1] = z1r * c1 + z1i * s1; ci[p1] = z1i * c1 - z1r * s1;
    float z2r = u0r - u2r, z2i = u0i - u2i;
    cr[p2] = z2r * c2 + z2i * s2; ci[p2] = z2i * c2 - z2r * s2;
    float z3r = u1r - u3i, z3i = u1i + u3r;            // u1 + i*u3
    cr[p3] = z3r * c3 + z3i * s3; ci[p3] = z3i * c3 - z3r * s3;
}

__device__ __forceinline__ void r4i_core(float* cr, float* ci, int p0, int p1, int p2, int p3,
                                         float c1, float s1, float c2, float s2, float c3, float s3) {
    float z0r = cr[p0], z0i = ci[p0];
    float z1r = cr[p1], z1i = ci[p1];
    float z2r = cr[p2], z2i = ci[p2];
    float z3r = cr[p3], z3i = ci[p3];
    float t1r = z1r * c1 - z1i * s1, t1i = z1i * c1 + z1r * s1;
    float t2r = z2r * c2 - z2i * s2, t2i = z2i * c2 + z2r * s2;
    float t3r = z3r * c3 - z3i * s3, t3i = z3i * c3 + z3r * s3;
    float u0r = z0r + t2r, u0i = z0i + t2i;
    float u1r = z0r - t2r, u1i = z0i - t2i;
    float u2r = t1r + t3r, u2i = t1i + t3i;
    float u3r = t1r - t3r, u3i = t1i - t3i;
    cr[p0] = u0r + u2r; ci[p0] = u0i + u2i;
    cr[p1] = u1r - u3i; ci[p1] = u1i + u3r;            // u1 + i*u3
    cr[p2] = u0r - u2r; ci[p2] = u0i - u2i;
    cr[p3] = u1r + u3i; ci[p3] = u1i - u3r;            // u1 - i*u3
}

// one radix-4 stage over 4 buffers with 1024 threads
#define STAGE4X(CORE, JEXPR, H, ANGEXPR)                                       \
    {                                                                          \
        _Pragma("unroll")                                                      \
        for (int half_ = 0; half_ < 2; ++half_) {                              \
            int b_ = tid + half_ * 1024;                                       \
            int i_ = b_ & 511;                                                 \
            float* cr_ = B + (b_ >> 9) * 4096;                                 \
            int j_ = (JEXPR);                                                  \
            int p0 = swz(j_), p1 = swz(j_ + (H)), p2 = swz(j_ + 2 * (H)),      \
                p3 = swz(j_ + 3 * (H));                                        \
            float s1, c1; __sincosf((ANGEXPR), &s1, &c1);                      \
            float c2 = c1 * c1 - s1 * s1, s2 = 2.f * c1 * s1;                  \
            float c3 = c1 * c2 - s1 * s2, s3 = s1 * c2 + c1 * s2;              \
            CORE(cr_, cr_ + 2048, p0, p1, p2, p3, c1, s1, c2, s2, c3, s3);     \
        }                                                                      \
    }                                                                          \
    __syncthreads();

// ---- fused: energy + 4x forward FFT + per-quarter tf max (512 blocks, 2/CU)
__global__ __launch_bounds__(1024, 8) void k_fwd(const float* __restrict__ env,
                                                 const float* __restrict__ noise,
                                                 const float* __restrict__ tf,
                                                 float* __restrict__ ws) {
    __shared__ float B[16384];   // 4 FFTs x (cr[2048], ci[2048]) = 64 KB
    int tid = threadIdx.x;
    int id = blockIdx.x;
    int xcd = id & 7, slot = id >> 3;
    int be = xcd * 16 + (slot >> 2);
    int fg = slot & 3;                       // f = fg*4 .. fg*4+3
    const float4* env4 = (const float4*)env;
    const float4* noi4 = (const float4*)noise;
    size_t base = (size_t)be * 16384 + fg;

    // issue ALL 8 global loads before any use (one latency exposure)
    float4 ev[4], nv[4];
#pragma unroll
    for (int it = 0; it < 4; ++it) {
        int n = it * 1024 + tid;
        ev[it] = env4[base + (size_t)n * 4];
        nv[it] = noi4[base + (size_t)n * 4];
    }
#pragma unroll
    for (int it = 0; it < 4; ++it) {
        int n = it * 1024 + tid;
        float4 e = ev[it], z = nv[it];
        float v0 = e.x * (z.x * 2.0f - 1.0f);
        float v1 = e.y * (z.y * 2.0f - 1.0f);
        float v2 = e.z * (z.z * 2.0f - 1.0f);
        float v3 = e.w * (z.w * 2.0f - 1.0f);
        int m = swz(n >> 1) + (n & 1) * 2048;   // cr at +0, ci at +2048
        B[m] = v0; B[4096 + m] = v1; B[8192 + m] = v2; B[12288 + m] = v3;
    }
    __syncthreads();
    // radix-2 DIF, h=1024 (twiddle shared across buffers)
    {
        int i = tid;
        int sj = swz(i), sjb = swz(i + 1024);
        float s, c; __sincosf((float)i * (TWO_PI / 2048.0f), &s, &c);
#pragma unroll
        for (int j4 = 0; j4 < 4; ++j4) {
            float* cr = B + j4 * 4096;
            float* ci = cr + 2048;
            float ar = cr[sj], ai = ci[sj], br = cr[sjb], bi = ci[sjb];
            float dr = ar - br, di = ai - bi;
            cr[sj] = ar + br; ci[sj] = ai + bi;
            cr[sjb] = dr * c + di * s; ci[sjb] = di * c - dr * s;
        }
    }
    __syncthreads();
    STAGE4X(r4f_core, (i_ >> 8) * 1024 + (i_ & 255), 256, (float)(i_ & 255) * (TWO_PI / 1024.0f));
    STAGE4X(r4f_core, (i_ >> 6) * 256 + (i_ & 63), 64, (float)(i_ & 63) * (TWO_PI / 256.0f));
    STAGE4X(r4f_core, (i_ & 31) * 64 + (i_ >> 5), 16, (float)(i_ >> 5) * (TWO_PI / 64.0f));
    STAGE4X(r4f_core, (i_ & 127) * 16 + (i_ >> 7), 4, (float)(i_ >> 7) * (TWO_PI / 16.0f));
    STAGE4X(r4f_core, i_ * 4, 1, 0.0f);
    // rfft unpack -> E (indices/twiddles shared across the 4 buffers)
    float2* Ebase = (float2*)(ws + OFF_E) + (size_t)(be * 16 + fg * 4) * 2049;
    for (int k = tid; k <= 1024; k += 1024) {
        int pk = swz(permf(k));
        int pm = swz(permf((2048 - k) & 2047));
        float s4, c4; __sincosf((float)k * (TWO_PI / 4096.0f), &s4, &c4);
#pragma unroll
        for (int j4 = 0; j4 < 4; ++j4) {
            float* cr = B + j4 * 4096;
            float* ci = cr + 2048;
            float zkr = cr[pk], zki = ci[pk], zmr = cr[pm], zmi = ci[pm];
            float xer = 0.5f * (zkr + zmr), xei = 0.5f * (zki - zmi);
            float xor_ = 0.5f * (zki + zmi), xoi = 0.5f * (zmr - zkr);
            float wr = xor_ * c4 + xoi * s4;
            float wi = xoi * c4 - xor_ * s4;
            float2* Eg = Ebase + (size_t)j4 * 2049;
            Eg[k] = make_float2(xer + wr, xei + wi);
            Eg[2048 - k] = make_float2(xer - wr, wi - xei);
        }
    }
    __syncthreads();
    // tf max over this block's bin quarter (reuses B)
    const float4* ab4 = (const float4*)(tf + (size_t)be * 65568);
    int b0 = fg * 513;
    int nb = (fg == 3) ? 510 : 513;          // 3*513 + 510 = 2049 bins
    float mx = 0.f;
    for (int u = tid; u < nb * 4; u += 1024) {
        int g = u >> 2, e = u & 3;
        int bin = b0 + g;
        float4 A = ab4[bin * 8 + e];
        float4 Bv = ab4[bin * 8 + e + 4];
        mx = fmaxf(mx, fmaxf(fmaxf(A.x * A.x + Bv.x * Bv.x, A.y * A.y + Bv.y * Bv.y),
                             fmaxf(A.z * A.z + Bv.z * Bv.z, A.w * A.w + Bv.w * Bv.w)));
    }
    B[tid] = mx;
    __syncthreads();
    for (int s = 512; s > 0; s >>= 1) {
        if (tid < s) B[tid] = fmaxf(B[tid], B[tid + s]);
        __syncthreads();
    }
    if (tid == 0) ws[OFF_MAXP + be * 4 + fg] = B[0];
}

// ---- per-bin recurrence on pair (k, 2048-k) + fused irfft pre-pack -> Z' natural order
__global__ __launch_bounds__(256) void k_recur(const float* __restrict__ tf,
                                               float* __restrict__ ws) {
    __shared__ float sm2lo[256 * 17], simlo[256 * 17];
    __shared__ float sm2hi[256 * 17], simhi[256 * 17];
    int tid = threadIdx.x;
    int be = blockIdx.y;
    int k0 = blockIdx.x << 8;          // 0,256,512,768
    int hi0 = 1793 - k0;               // hi bins [hi0, hi0+255]
    const float* tfb = tf + (size_t)be * 65568;
    const float4* ab4 = (const float4*)tfb;
    const float4* im4 = (const float4*)(tfb + 32784);

    for (int u = tid; u < 2048; u += 256) {
        int half = u >> 10, v = u & 1023;
        int g = v >> 2, e = v & 3;
        int bin = half ? (hi0 + g) : (k0 + g);
        float4 A = ab4[bin * 8 + e];
        float4 Bv = ab4[bin * 8 + e + 4];
        float4 I = im4[bin * 4 + e];
        int o = g * 17 + e * 4;
        float* sm = half ? sm2hi : sm2lo;
        float* si = half ? simhi : simlo;
        sm[o + 0] = A.x * A.x + Bv.x * Bv.x;
        sm[o + 1] = A.y * A.y + Bv.y * Bv.y;
        sm[o + 2] = A.z * A.z + Bv.z * Bv.z;
        sm[o + 3] = A.w * A.w + Bv.w * Bv.w;
        si[o + 0] = I.x; si[o + 1] = I.y; si[o + 2] = I.z; si[o + 3] = I.w;
    }
    __syncthreads();

    int k = k0 + tid;
    int m = 2048 - k;
    int rhi = 255 - tid;
    const float* mp = ws + OFF_MAXP + be * 4;
    float m2x = fmaxf(fmaxf(mp[0], mp[1]), fmaxf(mp[2], mp[3]));
    float rden = 1.0f / (sqrtf(m2x) + 1e-8f);
    const float2* Eb = (const float2*)(ws + OFF_E) + (size_t)be * 16 * 2049;
    float2* Zb = (float2*)(ws + OFF_Z) + (size_t)be * 16 * 2048;
    float2 evlo[16], evhi[16];
#pragma unroll
    for (int f = 0; f < 16; ++f) {
        evlo[f] = Eb[(size_t)f * 2049 + k];
        evhi[f] = Eb[(size_t)f * 2049 + m];
    }
    float ym = (k == 0) ? 0.0f : 1.0f;
    float s4, c4; __sincosf((float)k * (TWO_PI / 4096.0f), &s4, &c4);
    const float SCL = 1.0f / 2048.0f;
    float srl = 0.f, sil = 0.f, srh = 0.f, sih = 0.f;
#pragma unroll
    for (int f = 0; f < 16; ++f) {
        float mh = sqrtf(sm2lo[tid * 17 + f]) * rden;
        float ph = atan2f(simlo[tid * 17 + f], mh) * 3.14159265358979f;
        float sp, cp; __sincosf(ph, &sp, &cp);
        float Tr = mh * cp, Ti = mh * sp;
        sil *= ym;
        srl += evlo[f].x; sil += evlo[f].y;
        float nr = srl * Tr - sil * Ti;
        sil = srl * Ti + sil * Tr; srl = nr;
        float mh2 = sqrtf(sm2hi[rhi * 17 + f]) * rden;
        float ph2 = atan2f(simhi[rhi * 17 + f], mh2) * 3.14159265358979f;
        float sp2, cp2; __sincosf(ph2, &sp2, &cp2);
        float Tr2 = mh2 * cp2, Ti2 = mh2 * sp2;
        sih *= ym;
        srh += evhi[f].x; sih += evhi[f].y;
        float nr2 = srh * Tr2 - sih * Ti2;
        sih = srh * Ti2 + sih * Tr2; srh = nr2;
        float2* Zf = Zb + (size_t)f * 2048;
        if (k == 0) {
            float y0 = srl * SCL, yn = srh * SCL;
            Zf[0] = make_float2(0.5f * (y0 + yn), 0.5f * (y0 - yn));
        } else {
            float ykr = srl * SCL, yki = sil * SCL;
            float ymr = srh * SCL, ymi = sih * SCL;
            float er = 0.5f * (ykr + ymr), ei = 0.5f * (yki - ymi);
            float dr = ykr - ymr, di = yki + ymi;
            float orr = 0.5f * (dr * c4 - di * s4);
            float oi = 0.5f * (dr * s4 + di * c4);
            Zf[k] = make_float2(er - oi, ei + orr);
            Zf[m] = make_float2(er + oi, orr - ei);
        }
    }
    if (k0 == 0 && tid == 0) {   // bin 1024 (self-paired)
        float sr = 0.f, si = 0.f;
#pragma unroll
        for (int f = 0; f < 16; ++f) {
            float a = tfb[1024 * 32 + f];
            float b = tfb[1024 * 32 + 16 + f];
            float im = tfb[32784 + 1024 * 16 + f];
            float mh = sqrtf(a * a + b * b) * rden;
            float ph = atan2f(im, mh) * 3.14159265358979f;
            float sp, cp; __sincosf(ph, &sp, &cp);
            float Tr = mh * cp, Ti = mh * sp;
            float2 e = Eb[(size_t)f * 2049 + 1024];
            sr += e.x; si += e.y;
            float nr = sr * Tr - si * Ti;
            si = sr * Ti + si * Tr; sr = nr;
            Zb[(size_t)f * 2048 + 1024] = make_float2(sr * SCL, -si * SCL);
        }
    }
}

// ---- inverse FFT: 4 frames per block, 1024 threads, prefetched loads
__global__ __launch_bounds__(1024, 8) void k_fft_inv(float* __restrict__ ws) {
    __shared__ float B[16384];
    int tid = threadIdx.x;
    int be = blockIdx.x >> 2, fg = blockIdx.x & 3;
    const float2* Zbase = (const float2*)(ws + OFF_Z) + (size_t)(be * 16 + fg * 4) * 2048;
    float4 v[4];
#pragma unroll
    for (int j4 = 0; j4 < 4; ++j4)
        v[j4] = ((const float4*)(Zbase + (size_t)j4 * 2048))[tid];
#pragma unroll
    for (int j4 = 0; j4 < 4; ++j4) {
        float* cr = B + j4 * 4096;
        float* ci = cr + 2048;
        int n0 = tid * 2;
        int p0 = swz(permf(n0)), p1 = swz(permf(n0 + 1));
        cr[p0] = v[j4].x; ci[p0] = v[j4].y;
        cr[p1] = v[j4].z; ci[p1] = v[j4].w;
    }
    __syncthreads();
    STAGE4X(r4i_core, i_ * 4, 1, 0.0f);
    STAGE4X(r4i_core, (i_ & 127) * 16 + (i_ >> 7), 4, (float)(i_ >> 7) * (TWO_PI / 16.0f));
    STAGE4X(r4i_core, (i_ & 31) * 64 + (i_ >> 5), 16, (float)(i_ >> 5) * (TWO_PI / 64.0f));
    STAGE4X(r4i_core, (i_ >> 6) * 256 + (i_ & 63), 64, (float)(i_ & 63) * (TWO_PI / 256.0f));
    STAGE4X(r4i_core, (i_ >> 8) * 1024 + (i_ & 255), 256, (float)(i_ & 255) * (TWO_PI / 1024.0f));
    // radix-2 DIT, h=1024 (twiddle shared across buffers)
    {
        int i = tid;
        int sj = swz(i), sjb = swz(i + 1024);
        float s, c; __sincosf((float)i * (TWO_PI / 2048.0f), &s, &c);
#pragma unroll
        for (int j4 = 0; j4 < 4; ++j4) {
            float* cr = B + j4 * 4096;
            float* ci = cr + 2048;
            float br = cr[sjb], bi = ci[sjb];
            float tr = br * c - bi * s, ti2 = br * s + bi * c;
            float ar = cr[sj], ai = ci[sj];
            cr[sj] = ar + tr;  ci[sj] = ai + ti2;
            cr[sjb] = ar - tr; ci[sjb] = ai - ti2;
        }
    }
    __syncthreads();
    float2* Fbase = (float2*)(ws + OFF_ET) + (size_t)(be * 16 + fg * 4) * 2048;
#pragma unroll
    for (int j4 = 0; j4 < 4; ++j4) {
        float* cr = B + j4 * 4096;
        float* ci = cr + 2048;
        float2* Fg = Fbase + (size_t)j4 * 2048;
#pragma unroll
        for (int it = 0; it < 2; ++it) {
            int m = tid + it * 1024;
            Fg[m] = make_float2(cr[swz(m)], ci[swz(m)]);
        }
    }
}

// ---- gather + fused overlap-add (b uniform per block -> scalar indices)
__global__ __launch_bounds__(256) void k_segment(const float* __restrict__ ws,
                                                 const int* __restrict__ indices,
                                                 float* __restrict__ out) {
    __shared__ int ste[16];
    int tid = threadIdx.x;
    int b = blockIdx.y;
    if (tid < 16) ste[tid] = indices[b * 16 + tid] * 256;
    __syncthreads();
    int g = blockIdx.x * 256 + tid;
    int t = g << 2;
    const float* F = ws + OFF_ET;
    float4 acc = make_float4(0.f, 0.f, 0.f, 0.f);
#pragma unroll
    for (int e = 0; e < 16; ++e) {
        int te = ste[e];
        if (t >= te) {
            int d = t - te;
            int j = d >> 11, r = d & 2047;
            size_t base = (size_t)(b * 16 + e) * 65536;
            float4 v = *(const float4*)(F + base + j * 4096 + r);
            acc.x += v.x; acc.y += v.y; acc.z += v.z; acc.w += v.w;
            if (j >= 1) {
                float4 w = *(const float4*)(F + base + (j - 1) * 4096 + 2048 + r);
                acc.x += w.x; acc.y += w.y; acc.z += w.z; acc.w += w.w;
            }
        }
    }
    ((float4*)out)[(size_t)b * 8192 + g] = acc;
}

extern "C" void kernel_launch(void* const* d_in, const int* in_sizes, int n_in,
                              void* d_out, int out_size, void* d_ws, size_t ws_size,
                              hipStream_t stream) {
    const float* env = (const float*)d_in[0];
    const float* tf = (const float*)d_in[1];
    const float* noise = (const float*)d_in[2];
    const int* indices = (const int*)d_in[3];
    float* ws = (float*)d_ws;
    float* out = (float*)d_out;

    k_fwd<<<dim3(512), dim3(1024), 0, stream>>>(env, noise, tf, ws);
    k_recur<<<dim3(4, 128), dim3(256), 0, stream>>>(tf, ws);
    k_fft_inv<<<dim3(512), dim3(1024), 0, stream>>>(ws);
    k_segment<<<dim3(32, 8), dim3(256), 0, stream>>>(ws, indices, out);
}